// Round 9
// baseline (297.654 us; speedup 1.0000x reference)
//
#include <hip/hip_runtime.h>
#include <hip/hip_bf16.h>

typedef __attribute__((ext_vector_type(8))) short bf16x8;
typedef __attribute__((ext_vector_type(4))) float f32x4;

#define HD 256   // hidden size (K of the big GEMM)
#define NB 32    // batch
#define NT 4096  // timesteps
#define NE 8192  // edges per graph
#define N2 512   // 2*H (N of the big GEMM)

static __device__ __forceinline__ unsigned short f2bf(float f) {
  unsigned int u = __float_as_uint(f);
  u += 0x7fff + ((u >> 16) & 1);  // round-to-nearest-even
  return (unsigned short)(u >> 16);
}
static __device__ __forceinline__ short4 cvt4(float4 a) {
  return make_short4((short)f2bf(a.x), (short)f2bf(a.y),
                     (short)f2bf(a.z), (short)f2bf(a.w));
}
// tanh(x) = 1 - 2/(e^{2x}+1); e^{2x} via exp2. No clamp needed: x->+inf
// gives exp=inf, rcp=0, tanh=1; x->-inf gives exp=0, tanh=-1. 5 VALU inst.
static __device__ __forceinline__ float fast_tanh(float x) {
  float e = __builtin_amdgcn_exp2f(x * 2.8853900817779268f);  // 2/ln2
  return __builtin_fmaf(-2.f, __builtin_amdgcn_rcpf(e + 1.f), 1.f);
}

// Fused prep:
//  blocks 0..255   : cvecT[n][b] = b_attn[n] + hidden[b] . W_attn[n][0:256]
//  blocks 256..383 : Wbf[n*256+k] = bf16(W_attn[n][256+k])   (one-time convert)
__global__ __launch_bounds__(256) void prep(
    const float* __restrict__ hidden, const float* __restrict__ Wattn,
    const float* __restrict__ battn, float* __restrict__ cvecT,
    short* __restrict__ Wbf) {
  const int tid = threadIdx.x;
  if (blockIdx.x < 256) {
    __shared__ float Ws[64 * 260];
    __shared__ float Hs[HD];
    const int chunk = blockIdx.x & 7;
    const int b = blockIdx.x >> 3;
#pragma unroll
    for (int it = 0; it < 16; ++it) {
      int f = it * 1024 + tid * 4;
      int i = f >> 8, k = f & 255;
      float4 w4 = *(const float4*)(Wattn + (chunk * 64 + i) * N2 + k);
      *(float4*)&Ws[i * 260 + k] = w4;
    }
    if (tid < 64)
      *(float4*)&Hs[tid * 4] = *(const float4*)(hidden + b * HD + tid * 4);
    __syncthreads();
    const int nl = tid >> 2;
    const int kb = (tid & 3) * 64;
    float sum = 0.f;
#pragma unroll
    for (int z = 0; z < 64; z += 4) {
      float4 h4 = *(const float4*)&Hs[kb + z];
      float4 w4 = *(const float4*)&Ws[nl * 260 + kb + z];
      sum = fmaf(h4.x, w4.x, sum);
      sum = fmaf(h4.y, w4.y, sum);
      sum = fmaf(h4.z, w4.z, sum);
      sum = fmaf(h4.w, w4.w, sum);
    }
    sum += __shfl_xor(sum, 1, 64);
    sum += __shfl_xor(sum, 2, 64);
    if ((tid & 3) == 0)
      cvecT[(chunk * 64 + nl) * NB + b] = sum + battn[chunk * 64 + nl];
  } else {
    int f = (blockIdx.x - 256) * 1024 + tid * 4;  // 0..131071 = n*256+k
    int n = f >> 8, k = f & 255;
    float4 w4 = *(const float4*)(Wattn + n * N2 + HD + k);
    *(short4*)(Wbf + f) = cvt4(w4);
  }
}

// scores[b][t] = sum_n v[n]*tanh(cvecT[n][b] + enc_row . Wbf[n])
// 64 rows/block, 4 col-passes of 32 cols/wave (breg = 64 VGPRs).
// R9: explicit one-iter A-frag prefetch (a_nxt) + sched_barrier(0x38F)
// (DS & compute may cross, VMEM fenced -> breg can't hoist/spill) +
// launch_bounds(256,2) for a 256-reg no-spill budget. Truncation-pack
// staging (A) and 5-inst tanh cut VALU ~35%.
__global__ __launch_bounds__(256, 2) void score_gemm(
    const float* __restrict__ enc, const short* __restrict__ Wbf,
    const float* __restrict__ cvecT, const float* __restrict__ vvec,
    float* __restrict__ scores) {
  __shared__ short As[64 * 256];  // 32 KB, swizzled
  __shared__ float part[4][64];
  const int tid = threadIdx.x;
  const int w = tid >> 6, lane = tid & 63, q = lane >> 4, m = lane & 15;
  const long row0 = (long)blockIdx.x * 64;

  // ---- stage A (64 rows x 256 k) fp32 -> bf16 (truncate), swizzled ----
  const float* src = enc + row0 * HD;
#pragma unroll
  for (int it = 0; it < 16; ++it) {
    int f = it * 1024 + tid * 4;
    float4 a4 = *(const float4*)(src + f);
    int r = f >> 8, k = f & 255;
    int slot = (k >> 3) ^ (r & 31);
    uint2 pk;
    pk.x = (__float_as_uint(a4.y) & 0xffff0000u) | (__float_as_uint(a4.x) >> 16);
    pk.y = (__float_as_uint(a4.w) & 0xffff0000u) | (__float_as_uint(a4.z) >> 16);
    *(uint2*)&As[(r * 32 + slot) * 8 + (k & 7)] = pk;
  }
  __syncthreads();

  float rowacc[4][4];
#pragma unroll
  for (int rt = 0; rt < 4; ++rt)
#pragma unroll
    for (int j = 0; j < 4; ++j) rowacc[rt][j] = 0.f;

#pragma unroll 1
  for (int cc = 0; cc < 4; ++cc) {
    const int nb = cc * 128 + w * 32;  // wave's col base this pass
    bf16x8 breg0[8], breg1[8];
    const short* bp0 = Wbf + (nb + m) * HD + q * 8;
    const short* bp1 = Wbf + (nb + 16 + m) * HD + q * 8;
#pragma unroll
    for (int kk = 0; kk < 8; ++kk) {
      breg0[kk] = *(const bf16x8*)(bp0 + kk * 32);
      breg1[kk] = *(const bf16x8*)(bp1 + kk * 32);
    }
    const float vv0 = vvec[nb + m];
    const float vv1 = vvec[nb + 16 + m];
    // cvecT rows needed: b = (rt&1)*16 + 4q+j
    const f32x4 cva0 = *(const f32x4*)(cvecT + (nb + m) * NB + q * 4);
    const f32x4 cvb0 = *(const f32x4*)(cvecT + (nb + m) * NB + 16 + q * 4);
    const f32x4 cva1 = *(const f32x4*)(cvecT + (nb + 16 + m) * NB + q * 4);
    const f32x4 cvb1 = *(const f32x4*)(cvecT + (nb + 16 + m) * NB + 16 + q * 4);

    bf16x8 a_cur[8], a_nxt[8];
    {
      const int r = m, rx = m & 31;
#pragma unroll
      for (int kk = 0; kk < 8; ++kk)
        a_cur[kk] = *(const bf16x8*)&As[(r * 32 + ((kk * 4 + q) ^ rx)) * 8];
    }

#pragma unroll
    for (int rt = 0; rt < 4; ++rt) {
      // prefetch next iter's A-frags (DS may cross the barrier below)
      if (rt < 3) {
        const int rn = (rt + 1) * 16 + m, rxn = rn & 31;
#pragma unroll
        for (int kk = 0; kk < 8; ++kk)
          a_nxt[kk] = *(const bf16x8*)&As[(rn * 32 + ((kk * 4 + q) ^ rxn)) * 8];
      }
      // two independent 4-deep chains per output tile (kk 0-3 / 4-7)
      f32x4 acc0a = {0.f, 0.f, 0.f, 0.f}, acc0b = {0.f, 0.f, 0.f, 0.f};
      f32x4 acc1a = {0.f, 0.f, 0.f, 0.f}, acc1b = {0.f, 0.f, 0.f, 0.f};
#pragma unroll
      for (int kk = 0; kk < 4; ++kk) {
        acc0a = __builtin_amdgcn_mfma_f32_16x16x32_bf16(a_cur[kk], breg0[kk], acc0a, 0, 0, 0);
        acc1a = __builtin_amdgcn_mfma_f32_16x16x32_bf16(a_cur[kk], breg1[kk], acc1a, 0, 0, 0);
      }
#pragma unroll
      for (int kk = 4; kk < 8; ++kk) {
        acc0b = __builtin_amdgcn_mfma_f32_16x16x32_bf16(a_cur[kk], breg0[kk], acc0b, 0, 0, 0);
        acc1b = __builtin_amdgcn_mfma_f32_16x16x32_bf16(a_cur[kk], breg1[kk], acc1b, 0, 0, 0);
      }
      const f32x4 acc0 = acc0a + acc0b;
      const f32x4 acc1 = acc1a + acc1b;
      // C/D layout: row = rt*16 + 4q+j, col = n; b = row & 31 = (rt&1)*16+4q+j
      if (rt & 1) {
#pragma unroll
        for (int j = 0; j < 4; ++j)
          rowacc[rt][j] += fast_tanh(acc0[j] + cvb0[j]) * vv0
                         + fast_tanh(acc1[j] + cvb1[j]) * vv1;
      } else {
#pragma unroll
        for (int j = 0; j < 4; ++j)
          rowacc[rt][j] += fast_tanh(acc0[j] + cva0[j]) * vv0
                         + fast_tanh(acc1[j] + cva1[j]) * vv1;
      }
#pragma unroll
      for (int kk = 0; kk < 8; ++kk) a_cur[kk] = a_nxt[kk];
      // compute + DS may cross (overlap/prefetch), VMEM may not (spill guard)
      __builtin_amdgcn_sched_barrier(0x38F);
    }
  }

  // ---- deferred reduction over the 16 m-lanes, then cross-wave combine ----
#pragma unroll
  for (int rt = 0; rt < 4; ++rt) {
#pragma unroll
    for (int j = 0; j < 4; ++j) {
      float e = rowacc[rt][j];
      e += __shfl_xor(e, 1, 64);
      e += __shfl_xor(e, 2, 64);
      e += __shfl_xor(e, 4, 64);
      e += __shfl_xor(e, 8, 64);
      if (m == 0) part[w][rt * 16 + 4 * q + j] = e;
    }
  }
  __syncthreads();
  if (tid < 64) {
    const long r = row0 + tid;  // flat row = t*NB + b
    scores[(r & 31) * NT + (r >> 5)] =
        part[0][tid] + part[1][tid] + part[2][tid] + part[3][tid];
  }
}

// Per batch row: softmax over T (unnormalized exp in LDS), LDS-atomic edge
// scatter, then out = 0.1 * scattered * (1/sum). One block per batch row.
__global__ __launch_bounds__(1024) void softmax_scatter(
    const float* __restrict__ sc, const int* __restrict__ esrc,
    const int* __restrict__ edst, float* __restrict__ out) {
  __shared__ float wsv[NT];
  __shared__ float asv[NT];
  __shared__ float rtmp[16];
  __shared__ float rres;
  const int b = blockIdx.x;
  const int tid = threadIdx.x;
  const int wid = tid >> 6, lane = tid & 63;
  float s[4];
  float mx = -1e30f;
#pragma unroll
  for (int p = 0; p < 4; ++p) {
    s[p] = sc[b * NT + tid + p * 1024];
    mx = fmaxf(mx, s[p]);
  }
#pragma unroll
  for (int d = 32; d >= 1; d >>= 1) mx = fmaxf(mx, __shfl_xor(mx, d, 64));
  if (lane == 0) rtmp[wid] = mx;
  __syncthreads();
  if (tid == 0) {
    float mm = rtmp[0];
#pragma unroll
    for (int i = 1; i < 16; ++i) mm = fmaxf(mm, rtmp[i]);
    rres = mm;
  }
  __syncthreads();
  mx = rres;
  float sm = 0.f;
#pragma unroll
  for (int p = 0; p < 4; ++p) {
    int i = tid + p * 1024;
    float e = __expf(s[p] - mx);
    wsv[i] = e;
    asv[i] = 0.f;
    sm += e;
  }
#pragma unroll
  for (int d = 32; d >= 1; d >>= 1) sm += __shfl_xor(sm, d, 64);
  if (lane == 0) rtmp[wid] = sm;
  __syncthreads();
  if (tid == 0) {
    float tt = 0.f;
#pragma unroll
    for (int i = 0; i < 16; ++i) tt += rtmp[i];
    rres = tt;
  }
  __syncthreads();
  const float inv = 1.0f / rres;

  for (int j = tid; j < NE; j += 1024) {
    int ss = esrc[b * NE + j];
    int dd = edst[b * NE + j];
    if (dd != ss + 1) atomicAdd(&asv[dd], wsv[ss]);
  }
  __syncthreads();
#pragma unroll
  for (int p = 0; p < 4; ++p) {
    int i = tid + p * 1024;
    out[b * NT + i] = 0.1f * asv[i] * inv;
  }
}

extern "C" void kernel_launch(void* const* d_in, const int* in_sizes, int n_in,
                              void* d_out, int out_size, void* d_ws, size_t ws_size,
                              hipStream_t stream) {
  const float* hidden = (const float*)d_in[0];
  const float* enc    = (const float*)d_in[1];
  const int*   esrc   = (const int*)d_in[2];
  const int*   edst   = (const int*)d_in[3];
  const float* Wattn  = (const float*)d_in[4];
  const float* battn  = (const float*)d_in[5];
  const float* vvec   = (const float*)d_in[6];
  float* out = (float*)d_out;

  char* ws = (char*)d_ws;
  float* cvecT  = (float*)ws;                    // 512*32*4   = 64 KB
  short* Wbf    = (short*)(ws + 65536);          // 512*256*2  = 256 KB
  float* scores = (float*)(ws + 65536 + 262144); // 32*4096*4  = 512 KB

  prep<<<384, 256, 0, stream>>>(hidden, Wattn, battn, cvecT, Wbf);
  score_gemm<<<(NB * NT) / 64, 256, 0, stream>>>(enc, Wbf, cvecT, vvec, scores);
  softmax_scatter<<<NB, 1024, 0, stream>>>(scores, esrc, edst, out);
}

// Round 10
// 279.271 us; speedup vs baseline: 1.0658x; 1.0658x over previous
//
#include <hip/hip_runtime.h>
#include <hip/hip_bf16.h>

typedef __attribute__((ext_vector_type(8))) short bf16x8;
typedef __attribute__((ext_vector_type(4))) float f32x4;

#define HD 256   // hidden size (K of the big GEMM)
#define NB 32    // batch
#define NT 4096  // timesteps
#define NE 8192  // edges per graph
#define N2 512   // 2*H (N of the big GEMM)

static __device__ __forceinline__ unsigned short f2bf(float f) {
  unsigned int u = __float_as_uint(f);
  u += 0x7fff + ((u >> 16) & 1);  // round-to-nearest-even
  return (unsigned short)(u >> 16);
}
static __device__ __forceinline__ short4 cvt4(float4 a) {
  return make_short4((short)f2bf(a.x), (short)f2bf(a.y),
                     (short)f2bf(a.z), (short)f2bf(a.w));
}
// tanh(x) = 1 - 2/(e^{2x}+1); e^{2x} via exp2. Saturates correctly at +-inf.
static __device__ __forceinline__ float fast_tanh(float x) {
  float e = __builtin_amdgcn_exp2f(x * 2.8853900817779268f);  // 2/ln2
  return __builtin_fmaf(-2.f, __builtin_amdgcn_rcpf(e + 1.f), 1.f);
}
// pack 8 fp32 (k-ascending) -> bf16x8 by truncation (validated R9)
static __device__ __forceinline__ bf16x8 pack8(float4 a, float4 b) {
  union { bf16x8 v; unsigned int u[4]; } r;
  r.u[0] = (__float_as_uint(a.y) & 0xffff0000u) | (__float_as_uint(a.x) >> 16);
  r.u[1] = (__float_as_uint(a.w) & 0xffff0000u) | (__float_as_uint(a.z) >> 16);
  r.u[2] = (__float_as_uint(b.y) & 0xffff0000u) | (__float_as_uint(b.x) >> 16);
  r.u[3] = (__float_as_uint(b.w) & 0xffff0000u) | (__float_as_uint(b.z) >> 16);
  return r.v;
}

#define GLDS16(g, l)                                                       \
  __builtin_amdgcn_global_load_lds(                                        \
      (const __attribute__((address_space(1))) unsigned int*)(g),          \
      (__attribute__((address_space(3))) unsigned int*)(l), 16, 0, 0)

// Fused prep:
//  blocks 0..255   : cvecT[n][b] = b_attn[n] + hidden[b] . W_attn[n][0:256]
//  blocks 256..383 : Wbf[n*256+k] = bf16(W_attn[n][256+k])   (one-time convert)
__global__ __launch_bounds__(256) void prep(
    const float* __restrict__ hidden, const float* __restrict__ Wattn,
    const float* __restrict__ battn, float* __restrict__ cvecT,
    short* __restrict__ Wbf) {
  const int tid = threadIdx.x;
  if (blockIdx.x < 256) {
    __shared__ float Ws[64 * 260];
    __shared__ float Hs[HD];
    const int chunk = blockIdx.x & 7;
    const int b = blockIdx.x >> 3;
#pragma unroll
    for (int it = 0; it < 16; ++it) {
      int f = it * 1024 + tid * 4;
      int i = f >> 8, k = f & 255;
      float4 w4 = *(const float4*)(Wattn + (chunk * 64 + i) * N2 + k);
      *(float4*)&Ws[i * 260 + k] = w4;
    }
    if (tid < 64)
      *(float4*)&Hs[tid * 4] = *(const float4*)(hidden + b * HD + tid * 4);
    __syncthreads();
    const int nl = tid >> 2;
    const int kb = (tid & 3) * 64;
    float sum = 0.f;
#pragma unroll
    for (int z = 0; z < 64; z += 4) {
      float4 h4 = *(const float4*)&Hs[kb + z];
      float4 w4 = *(const float4*)&Ws[nl * 260 + kb + z];
      sum = fmaf(h4.x, w4.x, sum);
      sum = fmaf(h4.y, w4.y, sum);
      sum = fmaf(h4.z, w4.z, sum);
      sum = fmaf(h4.w, w4.w, sum);
    }
    sum += __shfl_xor(sum, 1, 64);
    sum += __shfl_xor(sum, 2, 64);
    if ((tid & 3) == 0)
      cvecT[(chunk * 64 + nl) * NB + b] = sum + battn[chunk * 64 + nl];
  } else {
    int f = (blockIdx.x - 256) * 1024 + tid * 4;  // 0..131071 = n*256+k
    int n = f >> 8, k = f & 255;
    float4 w4 = *(const float4*)(Wattn + n * N2 + HD + k);
    *(short4*)(Wbf + f) = cvt4(w4);
  }
}

// m97-style 2-barrier K-loop GEMM, fused tanh/v-dot epilogue ONCE per block.
// Block = 64 M-rows x 512 N, 4 waves each owning 64M x 128N (acc[4][8] f32x4
// = 128 regs, full-K accumulation). BK=32, 8 K-steps. A staged fp32 via
// global_load_lds (XOR-swizzled chunk order on the GLOBAL side; LDS side is
// forced lane-contiguous), converted bf16 at frag-read. B (Wbf, bf16) staged
// likewise. No sched_barriers: the 2 syncthreads per step bound code motion.
__global__ __launch_bounds__(256, 2) void score_gemm(
    const float* __restrict__ enc, const short* __restrict__ Wbf,
    const float* __restrict__ cvecT, const float* __restrict__ vvec,
    float* __restrict__ scores) {
  __shared__ float As[512 * 4];   // 64 rows x 32 k fp32, 16B-chunk swizzled: 8 KB
  __shared__ short Bs[2048 * 8];  // 512 n x 32 k bf16, swizzled: 32 KB
  __shared__ float part[4][64];
  const int tid = threadIdx.x;
  const int w = tid >> 6, lane = tid & 63, q = lane >> 4, m = lane & 15;
  const int row0 = blockIdx.x * 64;

  f32x4 acc[4][8];
#pragma unroll
  for (int mi = 0; mi < 4; ++mi)
#pragma unroll
    for (int nf = 0; nf < 8; ++nf) acc[mi][nf] = (f32x4){0.f, 0.f, 0.f, 0.f};

#pragma unroll 1
  for (int ks = 0; ks < 8; ++ks) {
    const int k0 = ks * 32;
    __syncthreads();  // previous step's frag reads done; LDS reusable
    // ---- stage A: 512 chunks (slot S holds row r=S>>3, kc=(S&7)^(r&7)) ----
#pragma unroll
    for (int i = 0; i < 2; ++i) {
      const int S = (i * 4 + w) * 64 + lane;
      const int r = S >> 3;
      const int kc = (S & 7) ^ (r & 7);
      GLDS16(enc + (row0 + r) * HD + k0 + kc * 4, &As[(S & ~63) * 4]);
    }
    // ---- stage B: 2048 chunks (slot S: n=S>>2, kc=(S&3)^((n>>1)&3)) ----
#pragma unroll
    for (int i = 0; i < 8; ++i) {
      const int S = (i * 4 + w) * 64 + lane;
      const int n = S >> 2;
      const int kc = (S & 3) ^ ((n >> 1) & 3);
      GLDS16(Wbf + n * HD + k0 + kc * 8, &Bs[(S & ~63) * 8]);
    }
    __syncthreads();  // drains vmcnt before any frag read

    // ---- B frags: 8 per wave (n = w*128 + nf*16 + m), held across mi ----
    bf16x8 bfr[8];
#pragma unroll
    for (int nf = 0; nf < 8; ++nf) {
      const int n = w * 128 + nf * 16 + m;
      bfr[nf] = *(const bf16x8*)&Bs[(n * 4 + (q ^ ((n >> 1) & 3))) * 8];
    }
    // ---- A frags + MFMA ----
#pragma unroll
    for (int mi = 0; mi < 4; ++mi) {
      const int r = mi * 16 + m;
      float4 a0 = *(const float4*)&As[(r * 8 + ((2 * q) ^ (r & 7))) * 4];
      float4 a1 = *(const float4*)&As[(r * 8 + ((2 * q + 1) ^ (r & 7))) * 4];
      bf16x8 af = pack8(a0, a1);
#pragma unroll
      for (int nf = 0; nf < 8; ++nf)
        acc[mi][nf] = __builtin_amdgcn_mfma_f32_16x16x32_bf16(af, bfr[nf], acc[mi][nf], 0, 0, 0);
    }
  }

  // ---- epilogue: tanh + v-dot, reduce over this wave's 128 cols ----
  float p[4][4];
#pragma unroll
  for (int mi = 0; mi < 4; ++mi)
#pragma unroll
    for (int j = 0; j < 4; ++j) p[mi][j] = 0.f;

#pragma unroll
  for (int nf = 0; nf < 8; ++nf) {
    const int n = w * 128 + nf * 16 + m;
    const float vv = vvec[n];
    // C/D layout: M-coord = mi*16 + 4q+j, N-coord = n; b = M & 31
    const f32x4 cvA = *(const f32x4*)(cvecT + n * NB + 4 * q);        // mi even
    const f32x4 cvB = *(const f32x4*)(cvecT + n * NB + 16 + 4 * q);   // mi odd
#pragma unroll
    for (int mi = 0; mi < 4; ++mi) {
      const f32x4 cv = (mi & 1) ? cvB : cvA;
#pragma unroll
      for (int j = 0; j < 4; ++j)
        p[mi][j] += fast_tanh(acc[mi][nf][j] + cv[j]) * vv;
    }
  }
#pragma unroll
  for (int mi = 0; mi < 4; ++mi) {
#pragma unroll
    for (int j = 0; j < 4; ++j) {
      float e = p[mi][j];
      e += __shfl_xor(e, 1, 64);
      e += __shfl_xor(e, 2, 64);
      e += __shfl_xor(e, 4, 64);
      e += __shfl_xor(e, 8, 64);  // sum over the 16 m-lanes
      if (m == 0) part[w][mi * 16 + 4 * q + j] = e;
    }
  }
  __syncthreads();
  if (tid < 64) {
    const int r = row0 + tid;  // flat row = t*NB + b
    scores[(r & 31) * NT + (r >> 5)] =
        part[0][tid] + part[1][tid] + part[2][tid] + part[3][tid];
  }
}

// 32 blocks: per-b softmax max & sum; writes smax[b], sinv[b]=0.1/sum; zeroes out[b].
__global__ __launch_bounds__(1024) void softmax_norm(
    const float* __restrict__ sc, float* __restrict__ smax,
    float* __restrict__ sinv, float* __restrict__ out) {
  __shared__ float rtmp[16];
  __shared__ float rres;
  const int b = blockIdx.x;
  const int tid = threadIdx.x;
  const int wid = tid >> 6, lane = tid & 63;
  float s[4];
  float mx = -1e30f;
#pragma unroll
  for (int p = 0; p < 4; ++p) {
    s[p] = sc[b * NT + tid + p * 1024];
    mx = fmaxf(mx, s[p]);
  }
#pragma unroll
  for (int d = 32; d >= 1; d >>= 1) mx = fmaxf(mx, __shfl_xor(mx, d, 64));
  if (lane == 0) rtmp[wid] = mx;
  __syncthreads();
  if (tid == 0) {
    float mm = rtmp[0];
#pragma unroll
    for (int i = 1; i < 16; ++i) mm = fmaxf(mm, rtmp[i]);
    rres = mm;
  }
  __syncthreads();
  mx = rres;
  float sm = 0.f;
#pragma unroll
  for (int p = 0; p < 4; ++p) sm += __expf(s[p] - mx);
#pragma unroll
  for (int d = 32; d >= 1; d >>= 1) sm += __shfl_xor(sm, d, 64);
  if (lane == 0) rtmp[wid] = sm;
  __syncthreads();
  if (tid == 0) {
    float tt = 0.f;
#pragma unroll
    for (int i = 0; i < 16; ++i) tt += rtmp[i];
    smax[b] = mx;
    sinv[b] = 0.1f / tt;
  }
#pragma unroll
  for (int p = 0; p < 4; ++p) out[b * NT + tid + p * 1024] = 0.f;
}

// 1024 blocks x 256: one edge per thread; out[b][dst] += 0.1*softmax(sc)[src].
__global__ __launch_bounds__(256) void scatter(
    const float* __restrict__ sc, const float* __restrict__ smax,
    const float* __restrict__ sinv, const int* __restrict__ esrc,
    const int* __restrict__ edst, float* __restrict__ out) {
  const int idx = blockIdx.x * 256 + threadIdx.x;  // 0..262143
  const int b = idx >> 13, e = idx & (NE - 1);
  const int ss = esrc[b * NE + e];
  const int dd = edst[b * NE + e];
  const float wv = __expf(sc[b * NT + ss] - smax[b]) * sinv[b];
  if (dd != ss + 1) atomicAdd(out + b * NT + dd, wv);
}

extern "C" void kernel_launch(void* const* d_in, const int* in_sizes, int n_in,
                              void* d_out, int out_size, void* d_ws, size_t ws_size,
                              hipStream_t stream) {
  const float* hidden = (const float*)d_in[0];
  const float* enc    = (const float*)d_in[1];
  const int*   esrc   = (const int*)d_in[2];
  const int*   edst   = (const int*)d_in[3];
  const float* Wattn  = (const float*)d_in[4];
  const float* battn  = (const float*)d_in[5];
  const float* vvec   = (const float*)d_in[6];
  float* out = (float*)d_out;

  char* ws = (char*)d_ws;
  float* cvecT  = (float*)ws;                    // 512*32*4   = 64 KB
  short* Wbf    = (short*)(ws + 65536);          // 512*256*2  = 256 KB
  float* scores = (float*)(ws + 65536 + 262144); // 32*4096*4  = 512 KB
  float* smax   = (float*)(ws + 65536 + 262144 + 524288);        // 128 B
  float* sinv   = (float*)(ws + 65536 + 262144 + 524288 + 128);  // 128 B

  prep<<<384, 256, 0, stream>>>(hidden, Wattn, battn, cvecT, Wbf);
  score_gemm<<<(NB * NT) / 64, 256, 0, stream>>>(enc, Wbf, cvecT, vvec, scores);
  softmax_norm<<<NB, 1024, 0, stream>>>(scores, smax, sinv, out);
  scatter<<<(NB * NE) / 256, 256, 0, stream>>>(scores, smax, sinv, esrc, edst, out);
}